// Round 20
// baseline (178.964 us; speedup 1.0000x reference)
//
#include <hip/hip_runtime.h>
#include <hip/hip_fp16.h>
#include <math.h>

#define NN 10000
#define EE 320000
#define PP 200000
#define NTILES 320   // 10240/32 global 32-K tiles for W frag packing
#define KSPL 1024    // K floats per split (4 chunks of 256)
#define NSPL 10      // 10*1024 = 10240 >= 10000

typedef _Float16 h8v __attribute__((ext_vector_type(8)));  // 8 fp16 (A/B frag)
typedef __attribute__((ext_vector_type(4))) float f4v;     // 4 f32  (C/D frag)

#define GLOAD_LDS16(gsrc, ldst)                                                        \
    __builtin_amdgcn_global_load_lds((const __attribute__((address_space(1))) void*)(gsrc), \
                                     (__attribute__((address_space(3))) void*)(ldst), 16, 0, 0)

// fp32 -> fp16 RTNE bit pattern
__device__ __forceinline__ ushort f2h(float f) {
    union { _Float16 h; ushort u; } c;
    c.h = (_Float16)f;
    return c.u;
}

// ---------------- degree / norm ----------------
__global__ void k_deg_count(const int* __restrict__ dst, int* __restrict__ degi) {
    int e = blockIdx.x * blockDim.x + threadIdx.x;
    if (e < EE) atomicAdd(&degi[dst[e]], 1);
}

__global__ void k_dinv(const int* __restrict__ degi, float* __restrict__ dinv) {
    int n = blockIdx.x * blockDim.x + threadIdx.x;
    if (n < NN) dinv[n] = rsqrtf((float)(degi[n] + 1));  // +1 self loop
}

// ---------------- W1 -> fp16 frag order; ALSO zeroes degi and zp (folded memsets) ----------------
__global__ void k_wprep(const float* __restrict__ W1, ushort* __restrict__ wf,
                        int* __restrict__ degi, float* __restrict__ zp) {
    int t = blockIdx.x * blockDim.x + threadIdx.x;
    if (t < NN) degi[t] = 0;
    if (t < 256) zp[t] = 0.f;
    if (t >= NTILES * 2 * 64 * 8) return;
    int e = t & 7, lane = (t >> 3) & 63, ct = (t >> 9) & 1, g = t >> 10;
    int col = ct * 16 + (lane & 15);
    int k = g * 32 + (lane >> 4) * 8 + e;
    wf[t] = (k < NN) ? f2h(W1[(long)k * 32 + col]) : (ushort)0;
}

// ---------------- GEMM1: 1-wave blocks, CONTINUOUS 2-buffer pipeline ----------------
// 4 chunks of 256-K per block; all 64 W-frags preloaded to VGPRs BEFORE the x loads
// (in-loop vmcnt FIFO holds only x stages -> exact counted waits). Compute chunk c at
// vmcnt(16) while chunk c+1 flies; stream never drains to 0 until the end.
// LDS 2x16.6 KB = 33.3 KB -> 4 blocks/CU, each a continuous HBM stream.
__global__ __launch_bounds__(64) void k_gemm1(const float* __restrict__ x,
                                              const ushort* __restrict__ w1f,
                                              const float* __restrict__ zp,
                                              float* __restrict__ h1_part) {
    __shared__ __align__(16) float xs[2][16][260];   // 33,280 B -> 4 blocks/CU
    const int lane = threadIdx.x;      // 0..63 (one wave)
    const int fl = lane & 15;
    const int khi = lane >> 4;
    const int ks = blockIdx.y;         // K-split 0..9
    const int wrow0 = blockIdx.x * 16; // 625*16 = 10000
    const long NN2 = (long)NN * NN;

    // ---- W frags for ALL 4 chunks -> 64 VGPRs, issued FIRST (FIFO-oldest) ----
    h8v wr[4][8][2];
#pragma unroll
    for (int c = 0; c < 4; ++c)
#pragma unroll
        for (int kk = 0; kk < 8; ++kk)
#pragma unroll
            for (int ct = 0; ct < 2; ++ct)
                wr[c][kk][ct] = *(const h8v*)(w1f +
                    ((long)((ks * 32 + c * 8 + kk) * 2 + ct) * 64 + lane) * 8);

    // ---- x staging: chunk = 16 insts, each ONE ROW x 1 KB contiguous ----
    auto stage = [&](int buf, int c) {
        const int kbase = ks * KSPL + c * 256;
#pragma unroll
        for (int j = 0; j < 16; ++j) {
            long flat = (long)(wrow0 + j) * NN + kbase + lane * 4;
            const float* src = (flat + 4 <= NN2) ? (x + flat) : zp;
            GLOAD_LDS16(src, &xs[buf][j][0]);
        }
    };

    f4v acc0 = (f4v){0.f, 0.f, 0.f, 0.f};
    f4v acc1 = (f4v){0.f, 0.f, 0.f, 0.f};

    auto compute = [&](int buf, int c) {
#pragma unroll
        for (int kk = 0; kk < 8; ++kk) {
            const float4* ap = (const float4*)&xs[buf][fl][kk * 32 + khi * 8];
            float4 f0 = ap[0];
            float4 f1 = ap[1];
            union { h8v v; _Float16 h[8]; } a;
            a.h[0] = (_Float16)f0.x; a.h[1] = (_Float16)f0.y;
            a.h[2] = (_Float16)f0.z; a.h[3] = (_Float16)f0.w;
            a.h[4] = (_Float16)f1.x; a.h[5] = (_Float16)f1.y;
            a.h[6] = (_Float16)f1.z; a.h[7] = (_Float16)f1.w;
            acc0 = __builtin_amdgcn_mfma_f32_16x16x32_f16(a.v, wr[c][kk][0], acc0, 0, 0, 0);
            acc1 = __builtin_amdgcn_mfma_f32_16x16x32_f16(a.v, wr[c][kk][1], acc1, 0, 0, 0);
        }
    };

    stage(0, 0);                       // after W: FIFO = [W(64), x0(16)]
    stage(1, 1);                       // + x1(16)

#define WAITV(n) asm volatile("s_waitcnt vmcnt(" #n ")" ::: "memory"); __builtin_amdgcn_sched_barrier(0)
#define WAITL()  asm volatile("s_waitcnt lgkmcnt(0)" ::: "memory");    __builtin_amdgcn_sched_barrier(0)

    // c=0: W + x0 retired when <=16 outstanding (x1 still flying)
    WAITV(16); compute(0, 0); WAITL(); stage(0, 2);
    WAITV(16); compute(1, 1); WAITL(); stage(1, 3);
    WAITV(16); compute(0, 2);
    WAITV(0);  compute(1, 3);
#undef WAITV
#undef WAITL

    // ---- epilogue: plain stores to per-split partials (no atomics) ----
    const long pbase = (long)ks * NN * 32;
#pragma unroll
    for (int ct = 0; ct < 2; ++ct) {
        f4v a = ct ? acc1 : acc0;
        const int col = ct * 16 + fl;
#pragma unroll
        for (int r = 0; r < 4; ++r) {
            int g = wrow0 + khi * 4 + r;                 // C/D row = khi*4 + reg (m89)
            h1_part[pbase + (long)g * 32 + col] = a[r];
        }
    }
}

// ---------------- reduce 10 partials + self-loop init (fused; out1 packed f16) ----------------
__global__ void k_selfinit1(const float4* __restrict__ h1_part4, const float* __restrict__ dinv,
                            float4* __restrict__ h1_pre4, __half* __restrict__ out1h) {
    int t = blockIdx.x * blockDim.x + threadIdx.x;
    if (t >= NN * 8) return;
    float4 s = make_float4(0.f, 0.f, 0.f, 0.f);
#pragma unroll
    for (int ks = 0; ks < NSPL; ++ks) {
        float4 v = h1_part4[(long)ks * NN * 8 + t];
        s.x += v.x; s.y += v.y; s.z += v.z; s.w += v.w;
    }
    int n = t >> 3;
    float d2 = dinv[n] * dinv[n];
    h1_pre4[t] = s;
    __half2 lo = __floats2half2_rn(s.x * d2, s.y * d2);
    __half2 hi = __floats2half2_rn(s.z * d2, s.w * d2);
    union { struct { __half2 a, b; } h; uint2 u; } p;
    p.h.a = lo; p.h.b = hi;
    *(uint2*)(out1h + (long)t * 4) = p.u;     // 8B aligned: t*4 halves
}

// ---------------- scatter1: packed-f16 atomics (16 transactions/edge) ----------------
__global__ void k_scatter1(const int* __restrict__ src, const int* __restrict__ dst,
                           const float* __restrict__ dinv, const float* __restrict__ h1_pre,
                           __half2* __restrict__ out1h2) {
    int t = blockIdx.x * blockDim.x + threadIdx.x;
    if (t >= EE * 16) return;
    int e = t >> 4, p = t & 15;              // col pair 2p, 2p+1
    int s = src[e], d = dst[e];
    float nrm = dinv[s] * dinv[d];
    const float2 hv = *(const float2*)&h1_pre[s * 32 + p * 2];
    __half2 val = __floats2half2_rn(hv.x * nrm, hv.y * nrm);
    unsafeAtomicAdd(&out1h2[d * 16 + p], val);   // global_atomic_pk_add_f16
}

// ---------------- GEMM2 (fused): relu(out1+b1) @ W2 -> h2_pre, + out2 init (f16) ----------------
__global__ __launch_bounds__(256) void k_gemm2(const __half* __restrict__ out1h,
                                               const float* __restrict__ W2,
                                               const float* __restrict__ b1,
                                               const float* __restrict__ dinv,
                                               float* __restrict__ h2_pre,
                                               __half* __restrict__ out2h) {
    __shared__ float w2s[512];
    __shared__ float b1s[32];
    int tid = threadIdx.x;
    w2s[tid] = W2[tid & 511];
    if (tid < 256) w2s[256 + tid] = W2[256 + tid];
    if (tid < 32) b1s[tid] = b1[tid];
    __syncthreads();
    int c = tid & 15, yloc = tid >> 4;
    int n = blockIdx.x * 16 + yloc;
    if (n < NN) {
        float a = 0.f;
#pragma unroll
        for (int k = 0; k < 32; ++k) {
            float v = fmaxf(__half2float(out1h[n * 32 + k]) + b1s[k], 0.f);  // fused bias+ReLU
            a += v * w2s[k * 16 + c];
        }
        h2_pre[n * 16 + c] = a;
        float di = dinv[n];
        out2h[n * 16 + c] = __float2half(di * di * a);         // fused self-loop init (f16)
    }
}

// ---------------- scatter2: packed-f16 atomics (8 transactions/edge) ----------------
__global__ void k_scatter2(const int* __restrict__ src, const int* __restrict__ dst,
                           const float* __restrict__ dinv, const float* __restrict__ h2_pre,
                           __half2* __restrict__ out2h2) {
    int t = blockIdx.x * blockDim.x + threadIdx.x;
    if (t >= EE * 8) return;
    int e = t >> 3, p = t & 7;               // col pair 2p, 2p+1
    int s = src[e], d = dst[e];
    float nrm = dinv[s] * dinv[d];
    const float2 hv = *(const float2*)&h2_pre[s * 16 + p * 2];
    __half2 val = __floats2half2_rn(hv.x * nrm, hv.y * nrm);
    unsafeAtomicAdd(&out2h2[d * 8 + p], val);    // global_atomic_pk_add_f16
}

// ---------------- final: per-node partial dots with Wfc ----------------
__global__ void k_final2(const __half* __restrict__ out2h, const float* __restrict__ b2,
                         const float* __restrict__ Wfc, float* __restrict__ s_arr,
                         float* __restrict__ t_arr) {
    int n = blockIdx.x * blockDim.x + threadIdx.x;
    if (n >= NN) return;
    float s = 0.f, t = 0.f;
#pragma unroll
    for (int c = 0; c < 16; ++c) {
        float v = __half2float(out2h[n * 16 + c]) + b2[c];
        s += v * Wfc[c];
        t += v * Wfc[16 + c];
    }
    s_arr[n] = s;
    t_arr[n] = t;
}

// ---------------- pair scoring ----------------
__global__ void k_pairs(const int* __restrict__ pair, const float* __restrict__ s_arr,
                        const float* __restrict__ t_arr, const float* __restrict__ bfc,
                        float* __restrict__ out) {
    int p = blockIdx.x * blockDim.x + threadIdx.x;
    if (p >= PP) return;
    const int2 ab = ((const int2*)pair)[p];
    float z = s_arr[ab.x] + t_arr[ab.y] + bfc[0];
    out[p] = 1.f / (1.f + expf(-z));
}

extern "C" void kernel_launch(void* const* d_in, const int* in_sizes, int n_in,
                              void* d_out, int out_size, void* d_ws, size_t ws_size,
                              hipStream_t stream) {
    const float* x    = (const float*)d_in[0];
    const int*   edge = (const int*)d_in[1];   // [2][E]
    const int*   pair = (const int*)d_in[2];   // [P][2]
    const float* W1   = (const float*)d_in[3];
    const float* b1   = (const float*)d_in[4];
    const float* W2   = (const float*)d_in[5];
    const float* b2   = (const float*)d_in[6];
    const float* Wfc  = (const float*)d_in[7];
    const float* bfc  = (const float*)d_in[8];
    float* out = (float*)d_out;
    float* ws  = (float*)d_ws;

    const int* src = edge;
    const int* dst = edge + EE;

    // workspace layout (floats)
    int*    degi    = (int*)ws;            // N
    float*  dinv    = ws + NN;             // N
    float*  h1_pre  = ws + 2 * NN;         // 32N
    __half* out1h   = (__half*)(ws + 34 * NN);   // 32N halves = 16N floats of space
    float*  h2_pre  = ws + 66 * NN;        // 16N
    __half* out2h   = (__half*)(ws + 82 * NN);   // 16N halves = 8N floats of space
    float*  s_arr   = ws + 98 * NN;        // N
    float*  t_arr   = ws + 99 * NN;        // N
    float*  zp      = ws + 100 * NN;       // 256 floats zero page
    ushort* w1f     = (ushort*)(ws + 100 * NN + 256);   // 327,680 ushorts = 163,840 floats
    float*  h1_part = ws + 100 * NN + 256 + 163840;     // 10*32N floats = 12.8 MB

    // wprep also zeroes degi and zp (memset dispatches folded in)
    k_wprep<<<(NTILES * 2 * 64 * 8 + 255) / 256, 256, 0, stream>>>(W1, w1f, degi, zp);
    k_deg_count<<<(EE + 255) / 256, 256, 0, stream>>>(dst, degi);
    k_dinv<<<(NN + 255) / 256, 256, 0, stream>>>(degi, dinv);

    k_gemm1<<<dim3(625, NSPL), 64, 0, stream>>>(x, w1f, zp, h1_part);

    k_selfinit1<<<(NN * 8 + 255) / 256, 256, 0, stream>>>(
        (const float4*)h1_part, dinv, (float4*)h1_pre, out1h);

    k_scatter1<<<(EE * 16 + 255) / 256, 256, 0, stream>>>(src, dst, dinv, h1_pre,
                                                          (__half2*)out1h);

    k_gemm2<<<(NN + 15) / 16, 256, 0, stream>>>(out1h, W2, b1, dinv, h2_pre, out2h);

    k_scatter2<<<(EE * 8 + 255) / 256, 256, 0, stream>>>(src, dst, dinv, h2_pre,
                                                         (__half2*)out2h);

    k_final2<<<(NN + 255) / 256, 256, 0, stream>>>(out2h, b2, Wfc, s_arr, t_arr);
    k_pairs<<<(PP + 255) / 256, 256, 0, stream>>>(pair, s_arr, t_arr, bfc, out);
}

// Round 21
// 171.010 us; speedup vs baseline: 1.0465x; 1.0465x over previous
//
#include <hip/hip_runtime.h>
#include <hip/hip_fp16.h>
#include <math.h>

#define NN 10000
#define EE 320000
#define PP 200000
#define NTILES 320   // 10240/32 global 32-K tiles for W frag packing
#define KSPL 1024    // K floats per split (4 chunks of 256)
#define NSPL 10      // 10*1024 = 10240 >= 10000

typedef _Float16 h8v __attribute__((ext_vector_type(8)));  // 8 fp16 (A/B frag)
typedef __attribute__((ext_vector_type(4))) float f4v;     // 4 f32  (C/D frag)

#define GLOAD_LDS16(gsrc, ldst)                                                        \
    __builtin_amdgcn_global_load_lds((const __attribute__((address_space(1))) void*)(gsrc), \
                                     (__attribute__((address_space(3))) void*)(ldst), 16, 0, 0)

// fp32 -> fp16 RTNE bit pattern
__device__ __forceinline__ ushort f2h(float f) {
    union { _Float16 h; ushort u; } c;
    c.h = (_Float16)f;
    return c.u;
}

// ---------------- degree / norm ----------------
__global__ void k_deg_count(const int* __restrict__ dst, int* __restrict__ degi) {
    int e = blockIdx.x * blockDim.x + threadIdx.x;
    if (e < EE) atomicAdd(&degi[dst[e]], 1);
}

__global__ void k_dinv(const int* __restrict__ degi, float* __restrict__ dinv) {
    int n = blockIdx.x * blockDim.x + threadIdx.x;
    if (n < NN) dinv[n] = rsqrtf((float)(degi[n] + 1));  // +1 self loop
}

// ---------------- W1 -> fp16 frag order; ALSO zeroes degi and zp (folded memsets) ----------------
__global__ void k_wprep(const float* __restrict__ W1, ushort* __restrict__ wf,
                        int* __restrict__ degi, float* __restrict__ zp) {
    int t = blockIdx.x * blockDim.x + threadIdx.x;
    if (t < NN) degi[t] = 0;
    if (t < 256) zp[t] = 0.f;
    if (t >= NTILES * 2 * 64 * 8) return;
    int e = t & 7, lane = (t >> 3) & 63, ct = (t >> 9) & 1, g = t >> 10;
    int col = ct * 16 + (lane & 15);
    int k = g * 32 + (lane >> 4) * 8 + e;
    wf[t] = (k < NN) ? f2h(W1[(long)k * 32 + col]) : (ushort)0;
}

// ---------------- GEMM1: 1-wave one-shot blocks, 4 sequential 256-K chunks ----------------
// R18-proven (175.9 us total; gemm1 ~94 us): phase-decorrelated one-shot 1-wave
// blocks, 9 independent blocks/CU. Seven schedule variants tested; this is best.
__global__ __launch_bounds__(64) void k_gemm1(const float* __restrict__ x,
                                              const ushort* __restrict__ w1f,
                                              const float* __restrict__ zp,
                                              float* __restrict__ h1_part) {
    __shared__ __align__(16) float xs[16][260];   // 16,640 B -> 9 blocks/CU
    const int lane = threadIdx.x;      // 0..63 (one wave)
    const int fl = lane & 15;
    const int khi = lane >> 4;
    const int ks = blockIdx.y;         // K-split 0..9
    const int wrow0 = blockIdx.x * 16; // 625*16 = 10000
    const long NN2 = (long)NN * NN;

    f4v acc0 = (f4v){0.f, 0.f, 0.f, 0.f};
    f4v acc1 = (f4v){0.f, 0.f, 0.f, 0.f};

#pragma unroll
    for (int half = 0; half < 4; ++half) {
        const int kbase = ks * KSPL + half * 256;
        const int gbase8 = ks * 32 + half * 8;    // global 32-K tile base

        // stage x: 16 insts, each ONE ROW x 1 KB contiguous
#pragma unroll
        for (int j = 0; j < 16; ++j) {
            long flat = (long)(wrow0 + j) * NN + kbase + lane * 4;
            const float* src = (flat + 4 <= NN2) ? (x + flat) : zp;
            GLOAD_LDS16(src, &xs[j][0]);
        }
        // W frags -> 32 VGPRs (L2-resident w1f)
        h8v wr[8][2];
#pragma unroll
        for (int kk = 0; kk < 8; ++kk)
#pragma unroll
            for (int ct = 0; ct < 2; ++ct)
                wr[kk][ct] = *(const h8v*)(w1f + ((long)((gbase8 + kk) * 2 + ct) * 64 + lane) * 8);

        asm volatile("s_waitcnt vmcnt(0)" ::: "memory");   // x landed in LDS
        __builtin_amdgcn_sched_barrier(0);

#pragma unroll
        for (int kk = 0; kk < 8; ++kk) {
            const float4* ap = (const float4*)&xs[fl][kk * 32 + khi * 8];
            float4 f0 = ap[0];
            float4 f1 = ap[1];
            union { h8v v; _Float16 h[8]; } a;
            a.h[0] = (_Float16)f0.x; a.h[1] = (_Float16)f0.y;
            a.h[2] = (_Float16)f0.z; a.h[3] = (_Float16)f0.w;
            a.h[4] = (_Float16)f1.x; a.h[5] = (_Float16)f1.y;
            a.h[6] = (_Float16)f1.z; a.h[7] = (_Float16)f1.w;
            acc0 = __builtin_amdgcn_mfma_f32_16x16x32_f16(a.v, wr[kk][0], acc0, 0, 0, 0);
            acc1 = __builtin_amdgcn_mfma_f32_16x16x32_f16(a.v, wr[kk][1], acc1, 0, 0, 0);
        }
        asm volatile("s_waitcnt lgkmcnt(0)" ::: "memory");
        __builtin_amdgcn_sched_barrier(0);
    }

    const long pbase = (long)ks * NN * 32;
#pragma unroll
    for (int ct = 0; ct < 2; ++ct) {
        f4v a = ct ? acc1 : acc0;
        const int col = ct * 16 + fl;
#pragma unroll
        for (int r = 0; r < 4; ++r) {
            int g = wrow0 + khi * 4 + r;                 // C/D row = khi*4 + reg (m89)
            h1_part[pbase + (long)g * 32 + col] = a[r];
        }
    }
}

// ---------------- reduce 10 partials + self-loop init (fused; out1 packed f16) ----------------
__global__ void k_selfinit1(const float4* __restrict__ h1_part4, const float* __restrict__ dinv,
                            float4* __restrict__ h1_pre4, __half* __restrict__ out1h) {
    int t = blockIdx.x * blockDim.x + threadIdx.x;
    if (t >= NN * 8) return;
    float4 s = make_float4(0.f, 0.f, 0.f, 0.f);
#pragma unroll
    for (int ks = 0; ks < NSPL; ++ks) {
        float4 v = h1_part4[(long)ks * NN * 8 + t];
        s.x += v.x; s.y += v.y; s.z += v.z; s.w += v.w;
    }
    int n = t >> 3;
    float d2 = dinv[n] * dinv[n];
    h1_pre4[t] = s;
    __half2 lo = __floats2half2_rn(s.x * d2, s.y * d2);
    __half2 hi = __floats2half2_rn(s.z * d2, s.w * d2);
    union { struct { __half2 a, b; } h; uint2 u; } p;
    p.h.a = lo; p.h.b = hi;
    *(uint2*)(out1h + (long)t * 4) = p.u;     // 8B aligned: t*4 halves
}

// ---------------- scatter1: packed-f16 atomics (16 transactions/edge) ----------------
__global__ void k_scatter1(const int* __restrict__ src, const int* __restrict__ dst,
                           const float* __restrict__ dinv, const float* __restrict__ h1_pre,
                           __half2* __restrict__ out1h2) {
    int t = blockIdx.x * blockDim.x + threadIdx.x;
    if (t >= EE * 16) return;
    int e = t >> 4, p = t & 15;              // col pair 2p, 2p+1
    int s = src[e], d = dst[e];
    float nrm = dinv[s] * dinv[d];
    const float2 hv = *(const float2*)&h1_pre[s * 32 + p * 2];
    __half2 val = __floats2half2_rn(hv.x * nrm, hv.y * nrm);
    unsafeAtomicAdd(&out1h2[d * 16 + p], val);   // global_atomic_pk_add_f16
}

// ---------------- GEMM2 (fused): relu(out1+b1) @ W2 -> h2_pre, + out2 init (f16) ----------------
__global__ __launch_bounds__(256) void k_gemm2(const __half* __restrict__ out1h,
                                               const float* __restrict__ W2,
                                               const float* __restrict__ b1,
                                               const float* __restrict__ dinv,
                                               float* __restrict__ h2_pre,
                                               __half* __restrict__ out2h) {
    __shared__ float w2s[512];
    __shared__ float b1s[32];
    int tid = threadIdx.x;
    w2s[tid] = W2[tid & 511];
    if (tid < 256) w2s[256 + tid] = W2[256 + tid];
    if (tid < 32) b1s[tid] = b1[tid];
    __syncthreads();
    int c = tid & 15, yloc = tid >> 4;
    int n = blockIdx.x * 16 + yloc;
    if (n < NN) {
        float a = 0.f;
#pragma unroll
        for (int k = 0; k < 32; ++k) {
            float v = fmaxf(__half2float(out1h[n * 32 + k]) + b1s[k], 0.f);  // fused bias+ReLU
            a += v * w2s[k * 16 + c];
        }
        h2_pre[n * 16 + c] = a;
        float di = dinv[n];
        out2h[n * 16 + c] = __float2half(di * di * a);         // fused self-loop init (f16)
    }
}

// ---------------- scatter2: packed-f16 atomics (8 transactions/edge) ----------------
__global__ void k_scatter2(const int* __restrict__ src, const int* __restrict__ dst,
                           const float* __restrict__ dinv, const float* __restrict__ h2_pre,
                           __half2* __restrict__ out2h2) {
    int t = blockIdx.x * blockDim.x + threadIdx.x;
    if (t >= EE * 8) return;
    int e = t >> 3, p = t & 7;               // col pair 2p, 2p+1
    int s = src[e], d = dst[e];
    float nrm = dinv[s] * dinv[d];
    const float2 hv = *(const float2*)&h2_pre[s * 16 + p * 2];
    __half2 val = __floats2half2_rn(hv.x * nrm, hv.y * nrm);
    unsafeAtomicAdd(&out2h2[d * 8 + p], val);    // global_atomic_pk_add_f16
}

// ---------------- final: per-node partial dots with Wfc ----------------
__global__ void k_final2(const __half* __restrict__ out2h, const float* __restrict__ b2,
                         const float* __restrict__ Wfc, float* __restrict__ s_arr,
                         float* __restrict__ t_arr) {
    int n = blockIdx.x * blockDim.x + threadIdx.x;
    if (n >= NN) return;
    float s = 0.f, t = 0.f;
#pragma unroll
    for (int c = 0; c < 16; ++c) {
        float v = __half2float(out2h[n * 16 + c]) + b2[c];
        s += v * Wfc[c];
        t += v * Wfc[16 + c];
    }
    s_arr[n] = s;
    t_arr[n] = t;
}

// ---------------- pair scoring ----------------
__global__ void k_pairs(const int* __restrict__ pair, const float* __restrict__ s_arr,
                        const float* __restrict__ t_arr, const float* __restrict__ bfc,
                        float* __restrict__ out) {
    int p = blockIdx.x * blockDim.x + threadIdx.x;
    if (p >= PP) return;
    const int2 ab = ((const int2*)pair)[p];
    float z = s_arr[ab.x] + t_arr[ab.y] + bfc[0];
    out[p] = 1.f / (1.f + expf(-z));
}

extern "C" void kernel_launch(void* const* d_in, const int* in_sizes, int n_in,
                              void* d_out, int out_size, void* d_ws, size_t ws_size,
                              hipStream_t stream) {
    const float* x    = (const float*)d_in[0];
    const int*   edge = (const int*)d_in[1];   // [2][E]
    const int*   pair = (const int*)d_in[2];   // [P][2]
    const float* W1   = (const float*)d_in[3];
    const float* b1   = (const float*)d_in[4];
    const float* W2   = (const float*)d_in[5];
    const float* b2   = (const float*)d_in[6];
    const float* Wfc  = (const float*)d_in[7];
    const float* bfc  = (const float*)d_in[8];
    float* out = (float*)d_out;
    float* ws  = (float*)d_ws;

    const int* src = edge;
    const int* dst = edge + EE;

    // workspace layout (floats)
    int*    degi    = (int*)ws;            // N
    float*  dinv    = ws + NN;             // N
    float*  h1_pre  = ws + 2 * NN;         // 32N
    __half* out1h   = (__half*)(ws + 34 * NN);   // 32N halves = 16N floats of space
    float*  h2_pre  = ws + 66 * NN;        // 16N
    __half* out2h   = (__half*)(ws + 82 * NN);   // 16N halves = 8N floats of space
    float*  s_arr   = ws + 98 * NN;        // N
    float*  t_arr   = ws + 99 * NN;        // N
    float*  zp      = ws + 100 * NN;       // 256 floats zero page
    ushort* w1f     = (ushort*)(ws + 100 * NN + 256);   // 327,680 ushorts = 163,840 floats
    float*  h1_part = ws + 100 * NN + 256 + 163840;     // 10*32N floats = 12.8 MB

    // wprep also zeroes degi and zp (memset dispatches folded in)
    k_wprep<<<(NTILES * 2 * 64 * 8 + 255) / 256, 256, 0, stream>>>(W1, w1f, degi, zp);
    k_deg_count<<<(EE + 255) / 256, 256, 0, stream>>>(dst, degi);
    k_dinv<<<(NN + 255) / 256, 256, 0, stream>>>(degi, dinv);

    k_gemm1<<<dim3(625, NSPL), 64, 0, stream>>>(x, w1f, zp, h1_part);

    k_selfinit1<<<(NN * 8 + 255) / 256, 256, 0, stream>>>(
        (const float4*)h1_part, dinv, (float4*)h1_pre, out1h);

    k_scatter1<<<(EE * 16 + 255) / 256, 256, 0, stream>>>(src, dst, dinv, h1_pre,
                                                          (__half2*)out1h);

    k_gemm2<<<(NN + 15) / 16, 256, 0, stream>>>(out1h, W2, b1, dinv, h2_pre, out2h);

    k_scatter2<<<(EE * 8 + 255) / 256, 256, 0, stream>>>(src, dst, dinv, h2_pre,
                                                         (__half2*)out2h);

    k_final2<<<(NN + 255) / 256, 256, 0, stream>>>(out2h, b2, Wfc, s_arr, t_arr);
    k_pairs<<<(PP + 255) / 256, 256, 0, stream>>>(pair, s_arr, t_arr, bfc, out);
}